// Round 5
// baseline (117.414 us; speedup 1.0000x reference)
//
#include <hip/hip_runtime.h>
#include <math.h>

// Problem constants (B,C,H,W = 4,64,64,64)
#define N     4096          // H*W
#define B     4
#define C     64
#define DQK   8
#define DV    32
#define LOG2E 1.4426950408889634f
// 3-way row split: kind 0 = theta(8)+phi(8), kind 1 = g rows 0-15, kind 2 = g rows 16-31.
// Each thread reads its x column ONCE (64 floats) and computes 16 output rows.
#define PROJ_BLOCKS ((B * 3 * N) / 256)   // 192

typedef __attribute__((ext_vector_type(8)))  short  short8;   // 8 bf16 (4 VGPR)
typedef __attribute__((ext_vector_type(16))) float  float16;  // MFMA 32x32 acc

union U4S8 { int4 v; unsigned int u[4]; short8 s; };

__device__ __forceinline__ unsigned short f2bf(float f) {   // RNE
  union { float f; unsigned int u; } c; c.f = f;
  unsigned int r = c.u + 0x7FFF + ((c.u >> 16) & 1);
  return (unsigned short)(r >> 16);
}
__device__ __forceinline__ float bf2f(unsigned short h) {
  union { unsigned int u; float f; } c; c.u = ((unsigned int)h) << 16;
  return c.f;
}
__device__ __forceinline__ unsigned int fbits(float f) {
  union { float f; unsigned int u; } c; c.f = f; return c.u;
}
__device__ __forceinline__ int bitswap23(int n) {   // swap bits 2<->3 (involution)
  return (n & ~0xC) | ((n & 4) << 1) | ((n & 8) >> 1);
}

// ---------------------------------------------------------------------------
// Kernel 1 (fat): blocks [0,192) = projections -> UNSCALED bf16 buffers;
// blocks [192,196) = spectral-norm sigma (concurrent; scales consumed only by
// the attention kernel). Layouts identical to the verified kernel.
// ---------------------------------------------------------------------------
__global__ __launch_bounds__(256) void projsig_kernel(
    const float* __restrict__ x,
    const float* __restrict__ w_theta, const float* __restrict__ w_phi,
    const float* __restrict__ w_g,     const float* __restrict__ w_o,
    const float* __restrict__ u_theta, const float* __restrict__ u_phi,
    const float* __restrict__ u_g,     const float* __restrict__ u_o,
    float* __restrict__ scales,
    unsigned short* __restrict__ theta_bf,
    unsigned short* __restrict__ phi_bf,
    unsigned short* __restrict__ v_pack) {
  __shared__ float v1[64];
  int bid = blockIdx.x;
  int tid = threadIdx.x;

  if (bid >= PROJ_BLOCKS) {
    // ---- sigma: 1/sigma, sigma = ||t||^2/(||t||+eps), t = w * l2n(w^T u) ----
    int which = bid - PROJ_BLOCKS;
    const float* w; const float* u; int M, K;
    if      (which == 0) { w = w_theta; u = u_theta; M = DQK; K = C;  }
    else if (which == 1) { w = w_phi;   u = u_phi;   M = DQK; K = C;  }
    else if (which == 2) { w = w_g;     u = u_g;     M = DV;  K = C;  }
    else                 { w = w_o;     u = u_o;     M = C;   K = DV; }

    float acc = 0.f;
    if (tid < K) {
      for (int m = 0; m < M; ++m) acc += w[m * K + tid] * u[m];
    }
    float ss = acc * acc;
    #pragma unroll
    for (int off = 32; off; off >>= 1) ss += __shfl_xor(ss, off);
    float nrm = sqrtf(ss);
    if (tid < 64) v1[tid] = (tid < K) ? acc / (nrm + 1e-12f) : 0.f;
    __syncthreads();

    float t = 0.f;
    if (tid < M) {
      for (int k = 0; k < K; ++k) t += w[tid * K + k] * v1[k];
    }
    float ts = t * t;
    #pragma unroll
    for (int off = 32; off; off >>= 1) ts += __shfl_xor(ts, off);
    float tn = sqrtf(ts);
    if (tid == 0) scales[which] = (tn + 1e-12f) / ts;
    return;
  }

  // ---- projections ----
  int t  = bid * 256 + tid;   // [0, B*3*N)
  int n  = t & (N - 1);
  int bk = t >> 12;
  int kind = bk % 3;          // block-uniform (16 blocks per (b,kind))
  int b    = bk / 3;

  const float* xp = x + (size_t)b * C * N + n;
  float xv[C];
  #pragma unroll
  for (int c = 0; c < C; ++c) xv[c] = xp[(size_t)c * N];

  float o[16];
  if (kind == 0) {
    #pragma unroll
    for (int r = 0; r < 8; ++r) {
      const float* wr = w_theta + r * C;
      float a = 0.f;
      #pragma unroll
      for (int c = 0; c < C; ++c) a += wr[c] * xv[c];
      o[r] = a;
    }
    #pragma unroll
    for (int r = 0; r < 8; ++r) {
      const float* wr = w_phi + r * C;
      float a = 0.f;
      #pragma unroll
      for (int c = 0; c < C; ++c) a += wr[c] * xv[c];
      o[8 + r] = a;
    }
    U4S8 pt, pp;
    #pragma unroll
    for (int i = 0; i < 4; ++i) {
      pt.u[i] = ((unsigned int)f2bf(o[2 * i])) |
                ((unsigned int)f2bf(o[2 * i + 1]) << 16);
      pp.u[i] = ((unsigned int)f2bf(o[8 + 2 * i])) |
                ((unsigned int)f2bf(o[8 + 2 * i + 1]) << 16);
    }
    *(int4*)(theta_bf + ((size_t)b * N + n) * 8) = pt.v;
    *(int4*)(phi_bf   + ((size_t)b * N + n) * 8) = pp.v;
  } else {
    int c0base = (kind - 1) * 16;
    const float* wb = w_g + c0base * C;
    #pragma unroll
    for (int r = 0; r < 16; ++r) {
      const float* wr = wb + r * C;
      float a = 0.f;
      #pragma unroll
      for (int c = 0; c < C; ++c) a += wr[c] * xv[c];
      o[r] = a;
    }
    // slot index in permuted key space (identical layout to verified kernel)
    int m  = bitswap23(n);
    int q  = m >> 4;            // 16-key chunk
    int hf = (m >> 3) & 1;      // which half of the chunk
    int ii = m & 7;             // element within the 8-pack
    unsigned short* dst = v_pack + ((size_t)(b * 256 + q)) * 64 * 8;
    #pragma unroll
    for (int r = 0; r < 16; ++r) {
      int lane = (c0base + r) | (hf << 5);
      dst[lane * 8 + ii] = f2bf(o[r]);
    }
  }
}

// ---------------------------------------------------------------------------
// Kernel 2: fused MFMA attention + combine + w_o projection + residual.
// RESTRUCTURED to 8 waves (512 threads)/block: wave w handles keys
// [w*512, w*512+512) = 16 tiles of 32 keys. LDS 45 KB -> 2 blocks/CU
// co-resident -> the 512-block grid completes in ONE occupancy round
// (was 2 rounds with 1024-thread/78KB blocks), with one epilogue and one
// drain tail instead of two. Inner-loop math identical to verified kernel.
// ---------------------------------------------------------------------------
__global__ __launch_bounds__(512) void attn_kernel(
    const unsigned short* __restrict__ theta_bf,
    const unsigned short* __restrict__ phi_bf,
    const unsigned short* __restrict__ v_pack,
    const float* __restrict__ w_o, const float* __restrict__ scales,
    const float* __restrict__ gamma,
    const float* __restrict__ x, float* __restrict__ out) {
  __shared__ float po_lds[8][16][64];            // [wave][reg][lane] 32 KB
  __shared__ float l_lds[8][32];                 // 1 KB
  __shared__ float Lrcp[32];
  __shared__ float ot[DV][33];                   // normalized o tile, padded
  __shared__ float wsh[C * DV];                  // scaled w_o, 8 KB

  int bi = blockIdx.x;           // B * 128
  int qt = bi & 127;
  int b  = bi >> 7;
  int tid  = threadIdx.x;
  int lane = tid & 63;
  int wav  = tid >> 6;           // 0..7
  int half = lane >> 5;
  int l31  = lane & 31;
  int j    = qt * 32 + l31;      // query column

  float kappa = scales[0] * scales[1] * LOG2E;
  float swo   = scales[2] * scales[3] * gamma[0];
  for (int i = tid; i < C * DV; i += 512) wsh[i] = w_o[i] * swo;

  // phi B-frag: lane(n=j, k=half*8+i); zero high K-half (dqk=8 pad to 16).
  U4S8 phu; phu.u[0] = phu.u[1] = phu.u[2] = phu.u[3] = 0;
  if (half == 0) {
    U4S8 raw; raw.v = *(const int4*)(phi_bf + ((size_t)b * N + j) * 8);
    #pragma unroll
    for (int i = 0; i < 8; ++i)
      phu.s[i] = (short)f2bf(bf2f((unsigned short)raw.s[i]) * kappa);
  }
  short8 phB = phu.s;

  // Loop-invariant zero C-operand for the score MFMA.
  float16 z16;
  #pragma unroll
  for (int r = 0; r < 16; ++r) z16[r] = 0.f;

  float ls0 = 0.f, ls1 = 0.f, ls2 = 0.f, ls3 = 0.f;
  float16 o;
  #pragma unroll
  for (int r = 0; r < 16; ++r) o[r] = 0.f;

  int kstart = wav * 512;        // 512 keys per wave, 16 tiles

  #pragma unroll 2
  for (int tt = 0; tt < 16; ++tt) {
    int kb = kstart + tt * 32;
    int q1 = kb >> 4;            // 16-key chunk index (block-uniform)

    U4S8 ta;  ta.v  = *(const int4*)(theta_bf + ((size_t)b * N + kb + l31) * 8);
    const int4* vp = (const int4*)(v_pack + ((size_t)(b * 256 + q1)) * 64 * 8);
    U4S8 va1; va1.v = vp[lane];        // coalesced 16B/lane
    U4S8 va2; va2.v = vp[64 + lane];

    float16 sf = __builtin_amdgcn_mfma_f32_32x32x16_bf16(ta.s, phB, z16, 0, 0, 0);

    float p[16];
    #pragma unroll
    for (int r = 0; r < 16; ++r)
      p[r] = __builtin_amdgcn_exp2f(sf[r]);   // bare v_exp_f32; domain SN-bounded
    #pragma unroll
    for (int r = 0; r < 16; r += 4) {
      ls0 += p[r];
      ls1 += p[r + 1];
      ls2 += p[r + 2];
      ls3 += p[r + 3];
    }

    unsigned int pk[8];
    #pragma unroll
    for (int i = 0; i < 8; ++i)
      pk[i] = __builtin_amdgcn_perm(fbits(p[2 * i + 1]), fbits(p[2 * i]),
                                    0x07060302u);
    // V is stored key-permuted: C-layout regs ARE the B-operand fragments.
    U4S8 b1, b2;
    b1.u[0] = pk[0]; b1.u[1] = pk[1]; b1.u[2] = pk[2]; b1.u[3] = pk[3];
    b2.u[0] = pk[4]; b2.u[1] = pk[5]; b2.u[2] = pk[6]; b2.u[3] = pk[7];

    o = __builtin_amdgcn_mfma_f32_32x32x16_bf16(va1.s, b1.s, o, 0, 0, 0);
    o = __builtin_amdgcn_mfma_f32_32x32x16_bf16(va2.s, b2.s, o, 0, 0, 0);
  }

  float lsum = (ls0 + ls1) + (ls2 + ls3);

  // ---- stage partials to LDS (fp32) ----
  lsum += __shfl_xor(lsum, 32);          // full per-query l over this wave's keys
  if (half == 0) l_lds[wav][l31] = lsum;
  #pragma unroll
  for (int r = 0; r < 16; ++r)
    po_lds[wav][r][lane] = o[r];
  __syncthreads();

  // ---- reduce over the 8 waves: 512 threads -> 2 (reg,lane) cells each ----
  int cell0 = tid;                       // 0..511
  int cell1 = tid + 512;                 // 512..1023
  int rr0 = cell0 >> 6, ii0 = cell0 & 63;
  int rr1 = cell1 >> 6, ii1 = cell1 & 63;
  float ov0 = 0.f, ov1 = 0.f;
  #pragma unroll
  for (int w = 0; w < 8; ++w) {
    ov0 += po_lds[w][rr0][ii0];
    ov1 += po_lds[w][rr1][ii1];
  }
  if (tid < 32) {
    float L = 0.f;
    #pragma unroll
    for (int w = 0; w < 8; ++w) L += l_lds[w][tid];
    Lrcp[tid] = 1.f / L;                 // L > 0 always (p > 0)
  }
  __syncthreads();

  {
    int cc0 = (rr0 & 3) + 8 * (rr0 >> 2) + 4 * (ii0 >> 5);
    int jq0 = ii0 & 31;
    ot[cc0][jq0] = ov0 * Lrcp[jq0];
    int cc1 = (rr1 & 3) + 8 * (rr1 >> 2) + 4 * (ii1 >> 5);
    int jq1 = ii1 & 31;
    ot[cc1][jq1] = ov1 * Lrcp[jq1];
  }
  __syncthreads();

  // ---- w_o projection + residual: thread -> 4 output rows ----
  int j2  = tid & 31;
  int ocp = tid >> 5;                    // 0..15
  float a0 = 0.f, a1 = 0.f, a2 = 0.f, a3 = 0.f;
  #pragma unroll
  for (int c = 0; c < DV; ++c) {
    float ov = ot[c][j2];
    a0 = fmaf(wsh[(ocp     ) * DV + c], ov, a0);
    a1 = fmaf(wsh[(ocp + 16) * DV + c], ov, a1);
    a2 = fmaf(wsh[(ocp + 32) * DV + c], ov, a2);
    a3 = fmaf(wsh[(ocp + 48) * DV + c], ov, a3);
  }
  size_t base = (size_t)b * C * N + (size_t)qt * 32 + j2;
  out[base + (size_t)(ocp     ) * N] = a0 + x[base + (size_t)(ocp     ) * N];
  out[base + (size_t)(ocp + 16) * N] = a1 + x[base + (size_t)(ocp + 16) * N];
  out[base + (size_t)(ocp + 32) * N] = a2 + x[base + (size_t)(ocp + 32) * N];
  out[base + (size_t)(ocp + 48) * N] = a3 + x[base + (size_t)(ocp + 48) * N];
}

// ---------------------------------------------------------------------------
extern "C" void kernel_launch(void* const* d_in, const int* in_sizes, int n_in,
                              void* d_out, int out_size, void* d_ws, size_t ws_size,
                              hipStream_t stream) {
  const float* x       = (const float*)d_in[0];
  const float* w_theta = (const float*)d_in[1];
  const float* w_phi   = (const float*)d_in[2];
  const float* w_g     = (const float*)d_in[3];
  const float* w_o     = (const float*)d_in[4];
  const float* gamma   = (const float*)d_in[5];
  const float* u_theta = (const float*)d_in[6];
  const float* u_phi   = (const float*)d_in[8];
  const float* u_g     = (const float*)d_in[10];
  const float* u_o     = (const float*)d_in[12];
  float* out = (float*)d_out;

  float* ws = (float*)d_ws;
  float*          scales   = ws;                                   // 16 floats
  unsigned short* theta_bf = (unsigned short*)(ws + 16);           // B*N*8 bf16
  unsigned short* phi_bf   = theta_bf + (size_t)B * N * 8;         // B*N*8
  unsigned short* v_pack   = phi_bf   + (size_t)B * N * 8;         // B*256*64*8

  projsig_kernel<<<PROJ_BLOCKS + 4, 256, 0, stream>>>(
      x, w_theta, w_phi, w_g, w_o, u_theta, u_phi, u_g, u_o,
      scales, theta_bf, phi_bf, v_pack);
  attn_kernel<<<B * 128, 512, 0, stream>>>(
      theta_bf, phi_bf, v_pack, w_o, scales, gamma, x, out);
}

// Round 6
// 114.269 us; speedup vs baseline: 1.0275x; 1.0275x over previous
//
#include <hip/hip_runtime.h>
#include <math.h>

// Problem constants (B,C,H,W = 4,64,64,64)
#define N     4096          // H*W
#define B     4
#define C     64
#define DQK   8
#define DV    32
#define LOG2E 1.4426950408889634f
// 3-way row split: kind 0 = theta(8)+phi(8), kind 1 = g rows 0-15, kind 2 = g rows 16-31.
#define PROJ_BLOCKS ((B * 3 * N) / 256)   // 192

typedef __attribute__((ext_vector_type(8)))  short  short8;   // 8 bf16 (4 VGPR)
typedef __attribute__((ext_vector_type(16))) float  float16;  // MFMA 32x32 acc

union U4S8 { int4 v; unsigned int u[4]; short8 s; };

__device__ __forceinline__ unsigned short f2bf(float f) {   // RNE
  union { float f; unsigned int u; } c; c.f = f;
  unsigned int r = c.u + 0x7FFF + ((c.u >> 16) & 1);
  return (unsigned short)(r >> 16);
}
__device__ __forceinline__ float bf2f(unsigned short h) {
  union { unsigned int u; float f; } c; c.u = ((unsigned int)h) << 16;
  return c.f;
}
__device__ __forceinline__ unsigned int fbits(float f) {
  union { float f; unsigned int u; } c; c.f = f; return c.u;
}
__device__ __forceinline__ int bitswap23(int n) {   // swap bits 2<->3 (involution)
  return (n & ~0xC) | ((n & 4) << 1) | ((n & 8) >> 1);
}

// ---------------------------------------------------------------------------
// Kernel 1 (fat): blocks [0,192) = projections -> UNSCALED bf16 buffers;
// blocks [192,196) = spectral-norm sigma. Layouts identical to the verified
// kernel (theta_bf/phi_bf row-packs; v_pack bitswap23-permuted A-fragments).
// ---------------------------------------------------------------------------
__global__ __launch_bounds__(256) void projsig_kernel(
    const float* __restrict__ x,
    const float* __restrict__ w_theta, const float* __restrict__ w_phi,
    const float* __restrict__ w_g,     const float* __restrict__ w_o,
    const float* __restrict__ u_theta, const float* __restrict__ u_phi,
    const float* __restrict__ u_g,     const float* __restrict__ u_o,
    float* __restrict__ scales,
    unsigned short* __restrict__ theta_bf,
    unsigned short* __restrict__ phi_bf,
    unsigned short* __restrict__ v_pack) {
  __shared__ float v1[64];
  int bid = blockIdx.x;
  int tid = threadIdx.x;

  if (bid >= PROJ_BLOCKS) {
    // ---- sigma: 1/sigma, sigma = ||t||^2/(||t||+eps), t = w * l2n(w^T u) ----
    int which = bid - PROJ_BLOCKS;
    const float* w; const float* u; int M, K;
    if      (which == 0) { w = w_theta; u = u_theta; M = DQK; K = C;  }
    else if (which == 1) { w = w_phi;   u = u_phi;   M = DQK; K = C;  }
    else if (which == 2) { w = w_g;     u = u_g;     M = DV;  K = C;  }
    else                 { w = w_o;     u = u_o;     M = C;   K = DV; }

    float acc = 0.f;
    if (tid < K) {
      for (int m = 0; m < M; ++m) acc += w[m * K + tid] * u[m];
    }
    float ss = acc * acc;
    #pragma unroll
    for (int off = 32; off; off >>= 1) ss += __shfl_xor(ss, off);
    float nrm = sqrtf(ss);
    if (tid < 64) v1[tid] = (tid < K) ? acc / (nrm + 1e-12f) : 0.f;
    __syncthreads();

    float t = 0.f;
    if (tid < M) {
      for (int k = 0; k < K; ++k) t += w[tid * K + k] * v1[k];
    }
    float ts = t * t;
    #pragma unroll
    for (int off = 32; off; off >>= 1) ts += __shfl_xor(ts, off);
    float tn = sqrtf(ts);
    if (tid == 0) scales[which] = (tn + 1e-12f) / ts;
    return;
  }

  // ---- projections ----
  int t  = bid * 256 + tid;   // [0, B*3*N)
  int n  = t & (N - 1);
  int bk = t >> 12;
  int kind = bk % 3;          // block-uniform (16 blocks per (b,kind))
  int b    = bk / 3;

  const float* xp = x + (size_t)b * C * N + n;
  float xv[C];
  #pragma unroll
  for (int c = 0; c < C; ++c) xv[c] = xp[(size_t)c * N];

  float o[16];
  if (kind == 0) {
    #pragma unroll
    for (int r = 0; r < 8; ++r) {
      const float* wr = w_theta + r * C;
      float a = 0.f;
      #pragma unroll
      for (int c = 0; c < C; ++c) a += wr[c] * xv[c];
      o[r] = a;
    }
    #pragma unroll
    for (int r = 0; r < 8; ++r) {
      const float* wr = w_phi + r * C;
      float a = 0.f;
      #pragma unroll
      for (int c = 0; c < C; ++c) a += wr[c] * xv[c];
      o[8 + r] = a;
    }
    U4S8 pt, pp;
    #pragma unroll
    for (int i = 0; i < 4; ++i) {
      pt.u[i] = ((unsigned int)f2bf(o[2 * i])) |
                ((unsigned int)f2bf(o[2 * i + 1]) << 16);
      pp.u[i] = ((unsigned int)f2bf(o[8 + 2 * i])) |
                ((unsigned int)f2bf(o[8 + 2 * i + 1]) << 16);
    }
    *(int4*)(theta_bf + ((size_t)b * N + n) * 8) = pt.v;
    *(int4*)(phi_bf   + ((size_t)b * N + n) * 8) = pp.v;
  } else {
    int c0base = (kind - 1) * 16;
    const float* wb = w_g + c0base * C;
    #pragma unroll
    for (int r = 0; r < 16; ++r) {
      const float* wr = wb + r * C;
      float a = 0.f;
      #pragma unroll
      for (int c = 0; c < C; ++c) a += wr[c] * xv[c];
      o[r] = a;
    }
    // slot index in permuted key space (identical layout to verified kernel)
    int m  = bitswap23(n);
    int q  = m >> 4;            // 16-key chunk
    int hf = (m >> 3) & 1;      // which half of the chunk
    int ii = m & 7;             // element within the 8-pack
    unsigned short* dst = v_pack + ((size_t)(b * 256 + q)) * 64 * 8;
    #pragma unroll
    for (int r = 0; r < 16; ++r) {
      int lane = (c0base + r) | (hf << 5);
      dst[lane * 8 + ii] = f2bf(o[r]);
    }
  }
}

// ---------------------------------------------------------------------------
// Kernel 2: fused MFMA attention + combine + w_o projection + residual.
// THIS ROUND: 64 queries per block (grid 256 = B*64), 8 waves x 512 keys.
// Rationale: each block reads ALL of theta+V for its batch (~320 KB from
// L2/L3); with 32q/block that was 512 blocks x 320 KB = 160 MB of cache
// traffic (> exp2 floor). 64q/block halves it to 80 MB: the same 3 loads
// per 32-key tile now feed TWO query columns (2 score MFMAs, 32 exp2,
// 4 PV MFMAs). Total MFMA/exp2 counts unchanged; key partition per wave
// unchanged (same L-sum order -> same numerics). LDS 83 KB -> 1 block/CU.
// ---------------------------------------------------------------------------
__global__ __launch_bounds__(512) void attn_kernel(
    const unsigned short* __restrict__ theta_bf,
    const unsigned short* __restrict__ phi_bf,
    const unsigned short* __restrict__ v_pack,
    const float* __restrict__ w_o, const float* __restrict__ scales,
    const float* __restrict__ gamma,
    const float* __restrict__ x, float* __restrict__ out) {
  __shared__ float po_lds[8][32][64];            // [wave][reg(o0:0-15,o1:16-31)][lane] 64 KB
  __shared__ float l_lds[8][64];                 // 2 KB
  __shared__ float Lrcp[64];
  __shared__ float ot[DV][65];                   // normalized o tile (64 q), padded
  __shared__ float wsh[C * DV];                  // scaled w_o, 8 KB

  int bi = blockIdx.x;           // B * 64
  int qt = bi & 63;
  int b  = bi >> 6;
  int tid  = threadIdx.x;
  int lane = tid & 63;
  int wav  = tid >> 6;           // 0..7
  int half = lane >> 5;
  int l31  = lane & 31;
  int j0   = qt * 64 + l31;      // query column, set 0
  int j1   = j0 + 32;            // query column, set 1

  float kappa = scales[0] * scales[1] * LOG2E;
  float swo   = scales[2] * scales[3] * gamma[0];
  for (int i = tid; i < C * DV; i += 512) wsh[i] = w_o[i] * swo;

  // phi B-frags for both query sets: lane(n=j, k=half*8+i); high K-half zero.
  U4S8 ph0; ph0.u[0] = ph0.u[1] = ph0.u[2] = ph0.u[3] = 0;
  U4S8 ph1; ph1.u[0] = ph1.u[1] = ph1.u[2] = ph1.u[3] = 0;
  if (half == 0) {
    U4S8 r0; r0.v = *(const int4*)(phi_bf + ((size_t)b * N + j0) * 8);
    U4S8 r1; r1.v = *(const int4*)(phi_bf + ((size_t)b * N + j1) * 8);
    #pragma unroll
    for (int i = 0; i < 8; ++i) {
      ph0.s[i] = (short)f2bf(bf2f((unsigned short)r0.s[i]) * kappa);
      ph1.s[i] = (short)f2bf(bf2f((unsigned short)r1.s[i]) * kappa);
    }
  }
  short8 phB0 = ph0.s;
  short8 phB1 = ph1.s;

  // Loop-invariant zero C-operand for the score MFMAs.
  float16 z16;
  #pragma unroll
  for (int r = 0; r < 16; ++r) z16[r] = 0.f;

  float lsA0 = 0.f, lsA1 = 0.f;   // query set 0
  float lsB0 = 0.f, lsB1 = 0.f;   // query set 1
  float16 o0, o1;
  #pragma unroll
  for (int r = 0; r < 16; ++r) { o0[r] = 0.f; o1[r] = 0.f; }

  int kstart = wav * 512;        // 512 keys per wave, 16 tiles (unchanged)

  #pragma unroll 2
  for (int tt = 0; tt < 16; ++tt) {
    int kb = kstart + tt * 32;
    int q1 = kb >> 4;            // 16-key chunk index (block-uniform)

    U4S8 ta;  ta.v  = *(const int4*)(theta_bf + ((size_t)b * N + kb + l31) * 8);
    const int4* vp = (const int4*)(v_pack + ((size_t)(b * 256 + q1)) * 64 * 8);
    U4S8 va1; va1.v = vp[lane];        // coalesced 16B/lane
    U4S8 va2; va2.v = vp[64 + lane];

    // ---- query set 0 ----
    float16 sf0 = __builtin_amdgcn_mfma_f32_32x32x16_bf16(ta.s, phB0, z16, 0, 0, 0);
    float p0[16];
    #pragma unroll
    for (int r = 0; r < 16; ++r)
      p0[r] = __builtin_amdgcn_exp2f(sf0[r]);
    #pragma unroll
    for (int r = 0; r < 16; r += 2) {
      lsA0 += p0[r];
      lsA1 += p0[r + 1];
    }
    unsigned int pk0[8];
    #pragma unroll
    for (int i = 0; i < 8; ++i)
      pk0[i] = __builtin_amdgcn_perm(fbits(p0[2 * i + 1]), fbits(p0[2 * i]),
                                     0x07060302u);
    U4S8 b1, b2;
    b1.u[0] = pk0[0]; b1.u[1] = pk0[1]; b1.u[2] = pk0[2]; b1.u[3] = pk0[3];
    b2.u[0] = pk0[4]; b2.u[1] = pk0[5]; b2.u[2] = pk0[6]; b2.u[3] = pk0[7];
    o0 = __builtin_amdgcn_mfma_f32_32x32x16_bf16(va1.s, b1.s, o0, 0, 0, 0);
    o0 = __builtin_amdgcn_mfma_f32_32x32x16_bf16(va2.s, b2.s, o0, 0, 0, 0);

    // ---- query set 1 (reuses ta/va loads) ----
    float16 sf1 = __builtin_amdgcn_mfma_f32_32x32x16_bf16(ta.s, phB1, z16, 0, 0, 0);
    float p1[16];
    #pragma unroll
    for (int r = 0; r < 16; ++r)
      p1[r] = __builtin_amdgcn_exp2f(sf1[r]);
    #pragma unroll
    for (int r = 0; r < 16; r += 2) {
      lsB0 += p1[r];
      lsB1 += p1[r + 1];
    }
    unsigned int pk1[8];
    #pragma unroll
    for (int i = 0; i < 8; ++i)
      pk1[i] = __builtin_amdgcn_perm(fbits(p1[2 * i + 1]), fbits(p1[2 * i]),
                                     0x07060302u);
    U4S8 c1, c2;
    c1.u[0] = pk1[0]; c1.u[1] = pk1[1]; c1.u[2] = pk1[2]; c1.u[3] = pk1[3];
    c2.u[0] = pk1[4]; c2.u[1] = pk1[5]; c2.u[2] = pk1[6]; c2.u[3] = pk1[7];
    o1 = __builtin_amdgcn_mfma_f32_32x32x16_bf16(va1.s, c1.s, o1, 0, 0, 0);
    o1 = __builtin_amdgcn_mfma_f32_32x32x16_bf16(va2.s, c2.s, o1, 0, 0, 0);
  }

  float lsum0 = lsA0 + lsA1;
  float lsum1 = lsB0 + lsB1;

  // ---- stage partials to LDS (fp32) ----
  lsum0 += __shfl_xor(lsum0, 32);        // full per-query l over this wave's keys
  lsum1 += __shfl_xor(lsum1, 32);
  if (half == 0) {
    l_lds[wav][l31]      = lsum0;
    l_lds[wav][32 + l31] = lsum1;
  }
  #pragma unroll
  for (int r = 0; r < 16; ++r) {
    po_lds[wav][r][lane]      = o0[r];
    po_lds[wav][16 + r][lane] = o1[r];
  }
  __syncthreads();

  // ---- reduce over 8 waves: 512 threads x 4 (reg,lane) cells each ----
  float ov0 = 0.f, ov1 = 0.f, ov2 = 0.f, ov3 = 0.f;
  {
    int R0 = tid >> 6,          ii0 = tid & 63;          // cells 0..511
    int R1 = (tid + 512) >> 6,  ii1 = tid & 63;          // 512..1023
    int R2 = (tid + 1024) >> 6, ii2 = tid & 63;          // 1024..1535
    int R3 = (tid + 1536) >> 6, ii3 = tid & 63;          // 1536..2047
    #pragma unroll
    for (int w = 0; w < 8; ++w) {
      ov0 += po_lds[w][R0][ii0];
      ov1 += po_lds[w][R1][ii1];
      ov2 += po_lds[w][R2][ii2];
      ov3 += po_lds[w][R3][ii3];
    }
  }
  if (tid < 64) {
    float L = 0.f;
    #pragma unroll
    for (int w = 0; w < 8; ++w) L += l_lds[w][tid];
    Lrcp[tid] = 1.f / L;                 // L > 0 always (p > 0)
  }
  __syncthreads();

  {
    int ii = tid & 63;
    #pragma unroll
    for (int k = 0; k < 4; ++k) {
      int R  = (tid + 512 * k) >> 6;
      float ov = (k == 0) ? ov0 : (k == 1) ? ov1 : (k == 2) ? ov2 : ov3;
      int qs = R >> 4;                   // 0 -> o0 set, 1 -> o1 set
      int r  = R & 15;
      int cc = (r & 3) + 8 * (r >> 2) + 4 * (ii >> 5);   // channel
      int jq = (ii & 31) + 32 * qs;                      // query within tile
      ot[cc][jq] = ov * Lrcp[jq];
    }
  }
  __syncthreads();

  // ---- w_o projection + residual: thread -> 8 output rows ----
  int j2  = tid & 63;                    // query within tile
  int ocp = tid >> 6;                    // 0..7
  float a0 = 0.f, a1 = 0.f, a2 = 0.f, a3 = 0.f;
  float a4 = 0.f, a5 = 0.f, a6 = 0.f, a7 = 0.f;
  #pragma unroll
  for (int c = 0; c < DV; ++c) {
    float ov = ot[c][j2];
    a0 = fmaf(wsh[(ocp     ) * DV + c], ov, a0);
    a1 = fmaf(wsh[(ocp +  8) * DV + c], ov, a1);
    a2 = fmaf(wsh[(ocp + 16) * DV + c], ov, a2);
    a3 = fmaf(wsh[(ocp + 24) * DV + c], ov, a3);
    a4 = fmaf(wsh[(ocp + 32) * DV + c], ov, a4);
    a5 = fmaf(wsh[(ocp + 40) * DV + c], ov, a5);
    a6 = fmaf(wsh[(ocp + 48) * DV + c], ov, a6);
    a7 = fmaf(wsh[(ocp + 56) * DV + c], ov, a7);
  }
  size_t base = (size_t)b * C * N + (size_t)qt * 64 + j2;
  out[base + (size_t)(ocp     ) * N] = a0 + x[base + (size_t)(ocp     ) * N];
  out[base + (size_t)(ocp +  8) * N] = a1 + x[base + (size_t)(ocp +  8) * N];
  out[base + (size_t)(ocp + 16) * N] = a2 + x[base + (size_t)(ocp + 16) * N];
  out[base + (size_t)(ocp + 24) * N] = a3 + x[base + (size_t)(ocp + 24) * N];
  out[base + (size_t)(ocp + 32) * N] = a4 + x[base + (size_t)(ocp + 32) * N];
  out[base + (size_t)(ocp + 40) * N] = a5 + x[base + (size_t)(ocp + 40) * N];
  out[base + (size_t)(ocp + 48) * N] = a6 + x[base + (size_t)(ocp + 48) * N];
  out[base + (size_t)(ocp + 56) * N] = a7 + x[base + (size_t)(ocp + 56) * N];
}

// ---------------------------------------------------------------------------
extern "C" void kernel_launch(void* const* d_in, const int* in_sizes, int n_in,
                              void* d_out, int out_size, void* d_ws, size_t ws_size,
                              hipStream_t stream) {
  const float* x       = (const float*)d_in[0];
  const float* w_theta = (const float*)d_in[1];
  const float* w_phi   = (const float*)d_in[2];
  const float* w_g     = (const float*)d_in[3];
  const float* w_o     = (const float*)d_in[4];
  const float* gamma   = (const float*)d_in[5];
  const float* u_theta = (const float*)d_in[6];
  const float* u_phi   = (const float*)d_in[8];
  const float* u_g     = (const float*)d_in[10];
  const float* u_o     = (const float*)d_in[12];
  float* out = (float*)d_out;

  float* ws = (float*)d_ws;
  float*          scales   = ws;                                   // 16 floats
  unsigned short* theta_bf = (unsigned short*)(ws + 16);           // B*N*8 bf16
  unsigned short* phi_bf   = theta_bf + (size_t)B * N * 8;         // B*N*8
  unsigned short* v_pack   = phi_bf   + (size_t)B * N * 8;         // B*256*64*8

  projsig_kernel<<<PROJ_BLOCKS + 4, 256, 0, stream>>>(
      x, w_theta, w_phi, w_g, w_o, u_theta, u_phi, u_g, u_o,
      scales, theta_bf, phi_bf, v_pack);
  attn_kernel<<<B * 64, 512, 0, stream>>>(
      theta_bf, phi_bf, v_pack, w_o, scales, gamma, x, out);
}

// Round 7
// 111.276 us; speedup vs baseline: 1.0552x; 1.0269x over previous
//
#include <hip/hip_runtime.h>
#include <math.h>

// Problem constants (B,C,H,W = 4,64,64,64)
#define N     4096          // H*W
#define B     4
#define C     64
#define DQK   8
#define DV    32
#define LOG2E 1.4426950408889634f
// 3-way row split: kind 0 = theta(8)+phi(8), kind 1 = g rows 0-15, kind 2 = g rows 16-31.
// Grid remap (this round): bid = kind*64 + group, group = b*16 + nchunk.
// The 3 kind-blocks of a group are 64 apart -> same XCD (64 % 8 == 0), so the
// 2nd/3rd reads of each 64 KB x-slice hit that XCD's L2 instead of HBM.
#define PROJ_BLOCKS ((B * 3 * N) / 256)   // 192

typedef __attribute__((ext_vector_type(8)))  short  short8;   // 8 bf16 (4 VGPR)
typedef __attribute__((ext_vector_type(16))) float  float16;  // MFMA 32x32 acc

union U4S8 { int4 v; unsigned int u[4]; short8 s; };

__device__ __forceinline__ unsigned short f2bf(float f) {   // RNE
  union { float f; unsigned int u; } c; c.f = f;
  unsigned int r = c.u + 0x7FFF + ((c.u >> 16) & 1);
  return (unsigned short)(r >> 16);
}
__device__ __forceinline__ float bf2f(unsigned short h) {
  union { unsigned int u; float f; } c; c.u = ((unsigned int)h) << 16;
  return c.f;
}
__device__ __forceinline__ unsigned int fbits(float f) {
  union { float f; unsigned int u; } c; c.f = f; return c.u;
}
__device__ __forceinline__ int bitswap23(int n) {   // swap bits 2<->3 (involution)
  return (n & ~0xC) | ((n & 4) << 1) | ((n & 8) >> 1);
}

// ---------------------------------------------------------------------------
// Kernel 1 (fat): blocks [0,192) = projections -> UNSCALED bf16 buffers;
// blocks [192,196) = spectral-norm sigma. Write layouts identical to the
// verified kernel (theta_bf/phi_bf row-packs; v_pack bitswap23-permuted
// A-fragments). Only the bid->(kind,b,n) decode changed (XCD grouping).
// ---------------------------------------------------------------------------
__global__ __launch_bounds__(256) void projsig_kernel(
    const float* __restrict__ x,
    const float* __restrict__ w_theta, const float* __restrict__ w_phi,
    const float* __restrict__ w_g,     const float* __restrict__ w_o,
    const float* __restrict__ u_theta, const float* __restrict__ u_phi,
    const float* __restrict__ u_g,     const float* __restrict__ u_o,
    float* __restrict__ scales,
    unsigned short* __restrict__ theta_bf,
    unsigned short* __restrict__ phi_bf,
    unsigned short* __restrict__ v_pack) {
  __shared__ float v1[64];
  int bid = blockIdx.x;
  int tid = threadIdx.x;

  if (bid >= PROJ_BLOCKS) {
    // ---- sigma: 1/sigma, sigma = ||t||^2/(||t||+eps), t = w * l2n(w^T u) ----
    int which = bid - PROJ_BLOCKS;
    const float* w; const float* u; int M, K;
    if      (which == 0) { w = w_theta; u = u_theta; M = DQK; K = C;  }
    else if (which == 1) { w = w_phi;   u = u_phi;   M = DQK; K = C;  }
    else if (which == 2) { w = w_g;     u = u_g;     M = DV;  K = C;  }
    else                 { w = w_o;     u = u_o;     M = C;   K = DV; }

    float acc = 0.f;
    if (tid < K) {
      for (int m = 0; m < M; ++m) acc += w[m * K + tid] * u[m];
    }
    float ss = acc * acc;
    #pragma unroll
    for (int off = 32; off; off >>= 1) ss += __shfl_xor(ss, off);
    float nrm = sqrtf(ss);
    if (tid < 64) v1[tid] = (tid < K) ? acc / (nrm + 1e-12f) : 0.f;
    __syncthreads();

    float t = 0.f;
    if (tid < M) {
      for (int k = 0; k < K; ++k) t += w[tid * K + k] * v1[k];
    }
    float ts = t * t;
    #pragma unroll
    for (int off = 32; off; off >>= 1) ts += __shfl_xor(ts, off);
    float tn = sqrtf(ts);
    if (tid == 0) scales[which] = (tn + 1e-12f) / ts;
    return;
  }

  // ---- projections: bid = kind*64 + (b*16 + nchunk) ----
  int kind   = bid >> 6;            // 0..2, block-uniform
  int grp    = bid & 63;
  int b      = grp >> 4;
  int n      = (grp & 15) * 256 + tid;

  const float* xp = x + (size_t)b * C * N + n;
  float xv[C];
  #pragma unroll
  for (int c = 0; c < C; ++c) xv[c] = xp[(size_t)c * N];

  float o[16];
  if (kind == 0) {
    #pragma unroll
    for (int r = 0; r < 8; ++r) {
      const float* wr = w_theta + r * C;
      float a = 0.f;
      #pragma unroll
      for (int c = 0; c < C; ++c) a += wr[c] * xv[c];
      o[r] = a;
    }
    #pragma unroll
    for (int r = 0; r < 8; ++r) {
      const float* wr = w_phi + r * C;
      float a = 0.f;
      #pragma unroll
      for (int c = 0; c < C; ++c) a += wr[c] * xv[c];
      o[8 + r] = a;
    }
    U4S8 pt, pp;
    #pragma unroll
    for (int i = 0; i < 4; ++i) {
      pt.u[i] = ((unsigned int)f2bf(o[2 * i])) |
                ((unsigned int)f2bf(o[2 * i + 1]) << 16);
      pp.u[i] = ((unsigned int)f2bf(o[8 + 2 * i])) |
                ((unsigned int)f2bf(o[8 + 2 * i + 1]) << 16);
    }
    *(int4*)(theta_bf + ((size_t)b * N + n) * 8) = pt.v;
    *(int4*)(phi_bf   + ((size_t)b * N + n) * 8) = pp.v;
  } else {
    int c0base = (kind - 1) * 16;
    const float* wb = w_g + c0base * C;
    #pragma unroll
    for (int r = 0; r < 16; ++r) {
      const float* wr = wb + r * C;
      float a = 0.f;
      #pragma unroll
      for (int c = 0; c < C; ++c) a += wr[c] * xv[c];
      o[r] = a;
    }
    // slot index in permuted key space (identical layout to verified kernel)
    int m  = bitswap23(n);
    int q  = m >> 4;            // 16-key chunk
    int hf = (m >> 3) & 1;      // which half of the chunk
    int ii = m & 7;             // element within the 8-pack
    unsigned short* dst = v_pack + ((size_t)(b * 256 + q)) * 64 * 8;
    #pragma unroll
    for (int r = 0; r < 16; ++r) {
      int lane = (c0base + r) | (hf << 5);
      dst[lane * 8 + ii] = f2bf(o[r]);
    }
  }
}

// ---------------------------------------------------------------------------
// Kernel 2: fused MFMA attention + combine + w_o projection + residual.
// 64 queries per block (grid 256 = B*64), 8 waves x 512 keys. Each 32-key
// tile's 3 loads feed TWO query columns (2 score MFMAs, 32 exp2, 4 PV MFMAs).
// Verified at 114.27 us in R6 — unchanged this round.
// ---------------------------------------------------------------------------
__global__ __launch_bounds__(512) void attn_kernel(
    const unsigned short* __restrict__ theta_bf,
    const unsigned short* __restrict__ phi_bf,
    const unsigned short* __restrict__ v_pack,
    const float* __restrict__ w_o, const float* __restrict__ scales,
    const float* __restrict__ gamma,
    const float* __restrict__ x, float* __restrict__ out) {
  __shared__ float po_lds[8][32][64];            // [wave][reg(o0:0-15,o1:16-31)][lane] 64 KB
  __shared__ float l_lds[8][64];                 // 2 KB
  __shared__ float Lrcp[64];
  __shared__ float ot[DV][65];                   // normalized o tile (64 q), padded
  __shared__ float wsh[C * DV];                  // scaled w_o, 8 KB

  int bi = blockIdx.x;           // B * 64
  int qt = bi & 63;
  int b  = bi >> 6;
  int tid  = threadIdx.x;
  int lane = tid & 63;
  int wav  = tid >> 6;           // 0..7
  int half = lane >> 5;
  int l31  = lane & 31;
  int j0   = qt * 64 + l31;      // query column, set 0
  int j1   = j0 + 32;            // query column, set 1

  float kappa = scales[0] * scales[1] * LOG2E;
  float swo   = scales[2] * scales[3] * gamma[0];
  for (int i = tid; i < C * DV; i += 512) wsh[i] = w_o[i] * swo;

  // phi B-frags for both query sets: lane(n=j, k=half*8+i); high K-half zero.
  U4S8 ph0; ph0.u[0] = ph0.u[1] = ph0.u[2] = ph0.u[3] = 0;
  U4S8 ph1; ph1.u[0] = ph1.u[1] = ph1.u[2] = ph1.u[3] = 0;
  if (half == 0) {
    U4S8 r0; r0.v = *(const int4*)(phi_bf + ((size_t)b * N + j0) * 8);
    U4S8 r1; r1.v = *(const int4*)(phi_bf + ((size_t)b * N + j1) * 8);
    #pragma unroll
    for (int i = 0; i < 8; ++i) {
      ph0.s[i] = (short)f2bf(bf2f((unsigned short)r0.s[i]) * kappa);
      ph1.s[i] = (short)f2bf(bf2f((unsigned short)r1.s[i]) * kappa);
    }
  }
  short8 phB0 = ph0.s;
  short8 phB1 = ph1.s;

  // Loop-invariant zero C-operand for the score MFMAs.
  float16 z16;
  #pragma unroll
  for (int r = 0; r < 16; ++r) z16[r] = 0.f;

  float lsA0 = 0.f, lsA1 = 0.f;   // query set 0
  float lsB0 = 0.f, lsB1 = 0.f;   // query set 1
  float16 o0, o1;
  #pragma unroll
  for (int r = 0; r < 16; ++r) { o0[r] = 0.f; o1[r] = 0.f; }

  int kstart = wav * 512;        // 512 keys per wave, 16 tiles

  #pragma unroll 2
  for (int tt = 0; tt < 16; ++tt) {
    int kb = kstart + tt * 32;
    int q1 = kb >> 4;            // 16-key chunk index (block-uniform)

    U4S8 ta;  ta.v  = *(const int4*)(theta_bf + ((size_t)b * N + kb + l31) * 8);
    const int4* vp = (const int4*)(v_pack + ((size_t)(b * 256 + q1)) * 64 * 8);
    U4S8 va1; va1.v = vp[lane];        // coalesced 16B/lane
    U4S8 va2; va2.v = vp[64 + lane];

    // ---- query set 0 ----
    float16 sf0 = __builtin_amdgcn_mfma_f32_32x32x16_bf16(ta.s, phB0, z16, 0, 0, 0);
    float p0[16];
    #pragma unroll
    for (int r = 0; r < 16; ++r)
      p0[r] = __builtin_amdgcn_exp2f(sf0[r]);
    #pragma unroll
    for (int r = 0; r < 16; r += 2) {
      lsA0 += p0[r];
      lsA1 += p0[r + 1];
    }
    unsigned int pk0[8];
    #pragma unroll
    for (int i = 0; i < 8; ++i)
      pk0[i] = __builtin_amdgcn_perm(fbits(p0[2 * i + 1]), fbits(p0[2 * i]),
                                     0x07060302u);
    U4S8 b1, b2;
    b1.u[0] = pk0[0]; b1.u[1] = pk0[1]; b1.u[2] = pk0[2]; b1.u[3] = pk0[3];
    b2.u[0] = pk0[4]; b2.u[1] = pk0[5]; b2.u[2] = pk0[6]; b2.u[3] = pk0[7];
    o0 = __builtin_amdgcn_mfma_f32_32x32x16_bf16(va1.s, b1.s, o0, 0, 0, 0);
    o0 = __builtin_amdgcn_mfma_f32_32x32x16_bf16(va2.s, b2.s, o0, 0, 0, 0);

    // ---- query set 1 (reuses ta/va loads) ----
    float16 sf1 = __builtin_amdgcn_mfma_f32_32x32x16_bf16(ta.s, phB1, z16, 0, 0, 0);
    float p1[16];
    #pragma unroll
    for (int r = 0; r < 16; ++r)
      p1[r] = __builtin_amdgcn_exp2f(sf1[r]);
    #pragma unroll
    for (int r = 0; r < 16; r += 2) {
      lsB0 += p1[r];
      lsB1 += p1[r + 1];
    }
    unsigned int pk1[8];
    #pragma unroll
    for (int i = 0; i < 8; ++i)
      pk1[i] = __builtin_amdgcn_perm(fbits(p1[2 * i + 1]), fbits(p1[2 * i]),
                                     0x07060302u);
    U4S8 c1, c2;
    c1.u[0] = pk1[0]; c1.u[1] = pk1[1]; c1.u[2] = pk1[2]; c1.u[3] = pk1[3];
    c2.u[0] = pk1[4]; c2.u[1] = pk1[5]; c2.u[2] = pk1[6]; c2.u[3] = pk1[7];
    o1 = __builtin_amdgcn_mfma_f32_32x32x16_bf16(va1.s, c1.s, o1, 0, 0, 0);
    o1 = __builtin_amdgcn_mfma_f32_32x32x16_bf16(va2.s, c2.s, o1, 0, 0, 0);
  }

  float lsum0 = lsA0 + lsA1;
  float lsum1 = lsB0 + lsB1;

  // ---- stage partials to LDS (fp32) ----
  lsum0 += __shfl_xor(lsum0, 32);        // full per-query l over this wave's keys
  lsum1 += __shfl_xor(lsum1, 32);
  if (half == 0) {
    l_lds[wav][l31]      = lsum0;
    l_lds[wav][32 + l31] = lsum1;
  }
  #pragma unroll
  for (int r = 0; r < 16; ++r) {
    po_lds[wav][r][lane]      = o0[r];
    po_lds[wav][16 + r][lane] = o1[r];
  }
  __syncthreads();

  // ---- reduce over 8 waves: 512 threads x 4 (reg,lane) cells each ----
  float ov0 = 0.f, ov1 = 0.f, ov2 = 0.f, ov3 = 0.f;
  {
    int R0 = tid >> 6,          ii0 = tid & 63;          // cells 0..511
    int R1 = (tid + 512) >> 6,  ii1 = tid & 63;          // 512..1023
    int R2 = (tid + 1024) >> 6, ii2 = tid & 63;          // 1024..1535
    int R3 = (tid + 1536) >> 6, ii3 = tid & 63;          // 1536..2047
    #pragma unroll
    for (int w = 0; w < 8; ++w) {
      ov0 += po_lds[w][R0][ii0];
      ov1 += po_lds[w][R1][ii1];
      ov2 += po_lds[w][R2][ii2];
      ov3 += po_lds[w][R3][ii3];
    }
  }
  if (tid < 64) {
    float L = 0.f;
    #pragma unroll
    for (int w = 0; w < 8; ++w) L += l_lds[w][tid];
    Lrcp[tid] = 1.f / L;                 // L > 0 always (p > 0)
  }
  __syncthreads();

  {
    int ii = tid & 63;
    #pragma unroll
    for (int k = 0; k < 4; ++k) {
      int R  = (tid + 512 * k) >> 6;
      float ov = (k == 0) ? ov0 : (k == 1) ? ov1 : (k == 2) ? ov2 : ov3;
      int qs = R >> 4;                   // 0 -> o0 set, 1 -> o1 set
      int r  = R & 15;
      int cc = (r & 3) + 8 * (r >> 2) + 4 * (ii >> 5);   // channel
      int jq = (ii & 31) + 32 * qs;                      // query within tile
      ot[cc][jq] = ov * Lrcp[jq];
    }
  }
  __syncthreads();

  // ---- w_o projection + residual: thread -> 8 output rows ----
  int j2  = tid & 63;                    // query within tile
  int ocp = tid >> 6;                    // 0..7
  float a0 = 0.f, a1 = 0.f, a2 = 0.f, a3 = 0.f;
  float a4 = 0.f, a5 = 0.f, a6 = 0.f, a7 = 0.f;
  #pragma unroll
  for (int c = 0; c < DV; ++c) {
    float ov = ot[c][j2];
    a0 = fmaf(wsh[(ocp     ) * DV + c], ov, a0);
    a1 = fmaf(wsh[(ocp +  8) * DV + c], ov, a1);
    a2 = fmaf(wsh[(ocp + 16) * DV + c], ov, a2);
    a3 = fmaf(wsh[(ocp + 24) * DV + c], ov, a3);
    a4 = fmaf(wsh[(ocp + 32) * DV + c], ov, a4);
    a5 = fmaf(wsh[(ocp + 40) * DV + c], ov, a5);
    a6 = fmaf(wsh[(ocp + 48) * DV + c], ov, a6);
    a7 = fmaf(wsh[(ocp + 56) * DV + c], ov, a7);
  }
  size_t base = (size_t)b * C * N + (size_t)qt * 64 + j2;
  out[base + (size_t)(ocp     ) * N] = a0 + x[base + (size_t)(ocp     ) * N];
  out[base + (size_t)(ocp +  8) * N] = a1 + x[base + (size_t)(ocp +  8) * N];
  out[base + (size_t)(ocp + 16) * N] = a2 + x[base + (size_t)(ocp + 16) * N];
  out[base + (size_t)(ocp + 24) * N] = a3 + x[base + (size_t)(ocp + 24) * N];
  out[base + (size_t)(ocp + 32) * N] = a4 + x[base + (size_t)(ocp + 32) * N];
  out[base + (size_t)(ocp + 40) * N] = a5 + x[base + (size_t)(ocp + 40) * N];
  out[base + (size_t)(ocp + 48) * N] = a6 + x[base + (size_t)(ocp + 48) * N];
  out[base + (size_t)(ocp + 56) * N] = a7 + x[base + (size_t)(ocp + 56) * N];
}

// ---------------------------------------------------------------------------
extern "C" void kernel_launch(void* const* d_in, const int* in_sizes, int n_in,
                              void* d_out, int out_size, void* d_ws, size_t ws_size,
                              hipStream_t stream) {
  const float* x       = (const float*)d_in[0];
  const float* w_theta = (const float*)d_in[1];
  const float* w_phi   = (const float*)d_in[2];
  const float* w_g     = (const float*)d_in[3];
  const float* w_o     = (const float*)d_in[4];
  const float* gamma   = (const float*)d_in[5];
  const float* u_theta = (const float*)d_in[6];
  const float* u_phi   = (const float*)d_in[8];
  const float* u_g     = (const float*)d_in[10];
  const float* u_o     = (const float*)d_in[12];
  float* out = (float*)d_out;

  float* ws = (float*)d_ws;
  float*          scales   = ws;                                   // 16 floats
  unsigned short* theta_bf = (unsigned short*)(ws + 16);           // B*N*8 bf16
  unsigned short* phi_bf   = theta_bf + (size_t)B * N * 8;         // B*N*8
  unsigned short* v_pack   = phi_bf   + (size_t)B * N * 8;         // B*256*64*8

  projsig_kernel<<<PROJ_BLOCKS + 4, 256, 0, stream>>>(
      x, w_theta, w_phi, w_g, w_o, u_theta, u_phi, u_g, u_o,
      scales, theta_bf, phi_bf, v_pack);
  attn_kernel<<<B * 64, 512, 0, stream>>>(
      theta_bf, phi_bf, v_pack, w_o, scales, gamma, x, out);
}